// Round 2
// baseline (283.186 us; speedup 1.0000x reference)
//
#include <hip/hip_runtime.h>

// Inputs (setup_inputs order):
//  0: coords        [100000*3] f32
//  1: pair_i        [8000000]  i32
//  2: pair_j        [8000000]  i32
//  3: pair_coul     [8000000]  f32
//  4: pair_a12      [8000000]  f32
//  5: pair_b6       [8000000]  f32
//  6: pair_b10      [8000000]  f32
//  7: pair14_i      [500000]   i32
//  8: pair14_j      [500000]   i32
//  9: pair14_coul   [500000]   f32
// 10: pair14_a12    [500000]   f32
// 11: pair14_b6     [500000]   f32
// 12: pair14_b10    [500000]   f32
// Output: [4] f32 = [e_coul, e_lj, e_coul14, e_lj14]
//
// Strategy: HBM-streaming-bound (204 MB of pair data; coords gather is
// L2-resident). f32 math (error ~1e9 vs threshold 1.6e13), f64 accumulators.
// int4/float4 loads: 4 pairs/thread/iter. One fused kernel produces per-block
// partials in d_ws; a 1-block finalize kernel reduces them.

#define BLOCK 256

__device__ __forceinline__ void pair_term(const float* __restrict__ coords,
                                          int i, int j, float coul, float a12,
                                          float b6, float b10,
                                          double& ec, double& ev) {
    int ia = i * 3, ja = j * 3;
    float dx = coords[ia + 0] - coords[ja + 0];
    float dy = coords[ia + 1] - coords[ja + 1];
    float dz = coords[ia + 2] - coords[ja + 2];
    float r2 = dx * dx + dy * dy + dz * dz;
    float inv_r2 = 1.0f / r2;
    float inv_r  = sqrtf(inv_r2);
    float inv_r6 = inv_r2 * inv_r2 * inv_r2;
    float e_c = coul * inv_r;
    float e_v = a12 * inv_r6 * inv_r6 - b6 * inv_r6
              - b10 * inv_r6 * inv_r2 * inv_r2;
    ec += (double)e_c;
    ev += (double)e_v;
}

__device__ __forceinline__ void scan_list(const float* __restrict__ coords,
                                          const int* __restrict__ ii,
                                          const int* __restrict__ jj,
                                          const float* __restrict__ coul,
                                          const float* __restrict__ a12,
                                          const float* __restrict__ b6,
                                          const float* __restrict__ b10,
                                          int n, int tid, int nthreads,
                                          double& ec, double& ev) {
    int n4 = n >> 2;
    for (int c = tid; c < n4; c += nthreads) {
        int4   i4 = ((const int4*)ii)[c];
        int4   j4 = ((const int4*)jj)[c];
        float4 c4 = ((const float4*)coul)[c];
        float4 a4 = ((const float4*)a12)[c];
        float4 b4 = ((const float4*)b6)[c];
        float4 h4 = ((const float4*)b10)[c];
        pair_term(coords, i4.x, j4.x, c4.x, a4.x, b4.x, h4.x, ec, ev);
        pair_term(coords, i4.y, j4.y, c4.y, a4.y, b4.y, h4.y, ec, ev);
        pair_term(coords, i4.z, j4.z, c4.z, a4.z, b4.z, h4.z, ec, ev);
        pair_term(coords, i4.w, j4.w, c4.w, a4.w, b4.w, h4.w, ec, ev);
    }
    // tail (n % 4 != 0)
    for (int p = (n4 << 2) + tid; p < n; p += nthreads) {
        pair_term(coords, ii[p], jj[p], coul[p], a12[p], b6[p], b10[p], ec, ev);
    }
}

__global__ __launch_bounds__(BLOCK) void fused_pair_kernel(
        const float* __restrict__ coords,
        const int* __restrict__ p_i, const int* __restrict__ p_j,
        const float* __restrict__ p_coul, const float* __restrict__ p_a12,
        const float* __restrict__ p_b6, const float* __restrict__ p_b10, int n_pair,
        const int* __restrict__ q_i, const int* __restrict__ q_j,
        const float* __restrict__ q_coul, const float* __restrict__ q_a12,
        const float* __restrict__ q_b6, const float* __restrict__ q_b10, int n_pair14,
        double* __restrict__ partials) {
    double ec = 0.0, ev = 0.0, ec14 = 0.0, ev14 = 0.0;
    int tid = blockIdx.x * blockDim.x + threadIdx.x;
    int nthreads = gridDim.x * blockDim.x;

    scan_list(coords, p_i, p_j, p_coul, p_a12, p_b6, p_b10, n_pair,
              tid, nthreads, ec, ev);
    scan_list(coords, q_i, q_j, q_coul, q_a12, q_b6, q_b10, n_pair14,
              tid, nthreads, ec14, ev14);

    // wave-64 shuffle reduction of 4 doubles
    for (int off = 32; off > 0; off >>= 1) {
        ec   += __shfl_down(ec,   off, 64);
        ev   += __shfl_down(ev,   off, 64);
        ec14 += __shfl_down(ec14, off, 64);
        ev14 += __shfl_down(ev14, off, 64);
    }

    __shared__ double s[BLOCK / 64][4];
    int lane = threadIdx.x & 63;
    int wid  = threadIdx.x >> 6;
    if (lane == 0) { s[wid][0] = ec; s[wid][1] = ev; s[wid][2] = ec14; s[wid][3] = ev14; }
    __syncthreads();

    if (threadIdx.x == 0) {
        double t0 = 0, t1 = 0, t2 = 0, t3 = 0;
        for (int w = 0; w < BLOCK / 64; ++w) {
            t0 += s[w][0]; t1 += s[w][1]; t2 += s[w][2]; t3 += s[w][3];
        }
        double* row = partials + (size_t)blockIdx.x * 4;
        row[0] = t0; row[1] = t1; row[2] = t2; row[3] = t3;
    }
}

__global__ __launch_bounds__(BLOCK) void finalize_kernel(
        const double* __restrict__ partials, int nrows,
        float* __restrict__ out) {
    double acc0 = 0, acc1 = 0, acc2 = 0, acc3 = 0;
    for (int r = threadIdx.x; r < nrows; r += blockDim.x) {
        const double* row = partials + (size_t)r * 4;
        acc0 += row[0]; acc1 += row[1]; acc2 += row[2]; acc3 += row[3];
    }
    for (int off = 32; off > 0; off >>= 1) {
        acc0 += __shfl_down(acc0, off, 64);
        acc1 += __shfl_down(acc1, off, 64);
        acc2 += __shfl_down(acc2, off, 64);
        acc3 += __shfl_down(acc3, off, 64);
    }
    __shared__ double s[BLOCK / 64][4];
    int lane = threadIdx.x & 63;
    int wid  = threadIdx.x >> 6;
    if (lane == 0) { s[wid][0] = acc0; s[wid][1] = acc1; s[wid][2] = acc2; s[wid][3] = acc3; }
    __syncthreads();
    if (threadIdx.x == 0) {
        double t0 = 0, t1 = 0, t2 = 0, t3 = 0;
        for (int w = 0; w < BLOCK / 64; ++w) {
            t0 += s[w][0]; t1 += s[w][1]; t2 += s[w][2]; t3 += s[w][3];
        }
        out[0] = (float)t0; out[1] = (float)t1;
        out[2] = (float)t2; out[3] = (float)t3;
    }
}

extern "C" void kernel_launch(void* const* d_in, const int* in_sizes, int n_in,
                              void* d_out, int out_size, void* d_ws, size_t ws_size,
                              hipStream_t stream) {
    const float* coords = (const float*)d_in[0];

    const int*   p_i    = (const int*)d_in[1];
    const int*   p_j    = (const int*)d_in[2];
    const float* p_coul = (const float*)d_in[3];
    const float* p_a12  = (const float*)d_in[4];
    const float* p_b6   = (const float*)d_in[5];
    const float* p_b10  = (const float*)d_in[6];
    int n_pair = in_sizes[1];

    const int*   q_i    = (const int*)d_in[7];
    const int*   q_j    = (const int*)d_in[8];
    const float* q_coul = (const float*)d_in[9];
    const float* q_a12  = (const float*)d_in[10];
    const float* q_b6   = (const float*)d_in[11];
    const float* q_b10  = (const float*)d_in[12];
    int n_pair14 = in_sizes[7];

    double* partials = (double*)d_ws;
    float*  out      = (float*)d_out;

    // 2048 blocks = 8 blocks/CU on 256 CUs; cap by scratch capacity (32 B/block).
    int blocks = 2048;
    size_t max_blocks = ws_size / (4 * sizeof(double));
    if ((size_t)blocks > max_blocks) blocks = (int)max_blocks;
    if (blocks < 1) blocks = 1;

    hipLaunchKernelGGL(fused_pair_kernel, dim3(blocks), dim3(BLOCK), 0, stream,
                       coords, p_i, p_j, p_coul, p_a12, p_b6, p_b10, n_pair,
                       q_i, q_j, q_coul, q_a12, q_b6, q_b10, n_pair14,
                       partials);

    hipLaunchKernelGGL(finalize_kernel, dim3(1), dim3(BLOCK), 0, stream,
                       partials, blocks, out);
}

// Round 4
// 256.889 us; speedup vs baseline: 1.1024x; 1.1024x over previous
//
#include <hip/hip_runtime.h>

// Inputs (setup_inputs order):
//  0: coords        [100000*3] f32
//  1: pair_i        [8000000]  i32
//  2: pair_j        [8000000]  i32
//  3: pair_coul     [8000000]  f32
//  4: pair_a12      [8000000]  f32
//  5: pair_b6       [8000000]  f32
//  6: pair_b10      [8000000]  f32
//  7..12: pair14 variants      [500000]
// Output: [4] f32 = [e_coul, e_lj, e_coul14, e_lj14]
//
// R2 diagnosis: gather-throughput-bound (751 GB/s HBM, VALU 9%). 6 random
// 4B coord loads/pair serialize in the TA. Fix: pre-pack coords to float4 in
// d_ws -> 2 dwordx4 gathers/pair; nontemporal vector loads for the once-read
// pair streams (ext_vector_type — HIP_vector_type is rejected by the builtin).

#define BLOCK 256
#define GRID  2048

typedef int   intx4   __attribute__((ext_vector_type(4)));
typedef float floatx4 __attribute__((ext_vector_type(4)));

__global__ void pack_coords_kernel(const float* __restrict__ coords,
                                   float4* __restrict__ packed, int natom) {
    int i = blockIdx.x * blockDim.x + threadIdx.x;
    if (i < natom) {
        packed[i] = make_float4(coords[3 * i + 0], coords[3 * i + 1],
                                coords[3 * i + 2], 0.0f);
    }
}

__device__ __forceinline__ void pair_term_packed(const float4* __restrict__ packed,
                                                 int i, int j, float coul, float a12,
                                                 float b6, float b10,
                                                 double& ec, double& ev) {
    float4 ci = packed[i];
    float4 cj = packed[j];
    float dx = ci.x - cj.x;
    float dy = ci.y - cj.y;
    float dz = ci.z - cj.z;
    float r2 = dx * dx + dy * dy + dz * dz;
    float inv_r2 = 1.0f / r2;
    float inv_r  = sqrtf(inv_r2);
    float inv_r6 = inv_r2 * inv_r2 * inv_r2;
    ec += (double)(coul * inv_r);
    ev += (double)(a12 * inv_r6 * inv_r6 - b6 * inv_r6
                 - b10 * inv_r6 * inv_r2 * inv_r2);
}

__device__ __forceinline__ void pair_term_direct(const float* __restrict__ coords,
                                                 int i, int j, float coul, float a12,
                                                 float b6, float b10,
                                                 double& ec, double& ev) {
    int ia = i * 3, ja = j * 3;
    float dx = coords[ia + 0] - coords[ja + 0];
    float dy = coords[ia + 1] - coords[ja + 1];
    float dz = coords[ia + 2] - coords[ja + 2];
    float r2 = dx * dx + dy * dy + dz * dz;
    float inv_r2 = 1.0f / r2;
    float inv_r  = sqrtf(inv_r2);
    float inv_r6 = inv_r2 * inv_r2 * inv_r2;
    ec += (double)(coul * inv_r);
    ev += (double)(a12 * inv_r6 * inv_r6 - b6 * inv_r6
                 - b10 * inv_r6 * inv_r2 * inv_r2);
}

__device__ __forceinline__ void scan_list(const float* __restrict__ coords,
                                          const float4* __restrict__ packed,
                                          const int* __restrict__ ii,
                                          const int* __restrict__ jj,
                                          const float* __restrict__ coul,
                                          const float* __restrict__ a12,
                                          const float* __restrict__ b6,
                                          const float* __restrict__ b10,
                                          int n, int tid, int nthreads,
                                          double& ec, double& ev) {
    int n4 = n >> 2;
    if (packed) {
        for (int c = tid; c < n4; c += nthreads) {
            intx4   i4 = __builtin_nontemporal_load(((const intx4*)ii) + c);
            intx4   j4 = __builtin_nontemporal_load(((const intx4*)jj) + c);
            floatx4 c4 = __builtin_nontemporal_load(((const floatx4*)coul) + c);
            floatx4 a4 = __builtin_nontemporal_load(((const floatx4*)a12) + c);
            floatx4 b4 = __builtin_nontemporal_load(((const floatx4*)b6) + c);
            floatx4 h4 = __builtin_nontemporal_load(((const floatx4*)b10) + c);
            pair_term_packed(packed, i4.x, j4.x, c4.x, a4.x, b4.x, h4.x, ec, ev);
            pair_term_packed(packed, i4.y, j4.y, c4.y, a4.y, b4.y, h4.y, ec, ev);
            pair_term_packed(packed, i4.z, j4.z, c4.z, a4.z, b4.z, h4.z, ec, ev);
            pair_term_packed(packed, i4.w, j4.w, c4.w, a4.w, b4.w, h4.w, ec, ev);
        }
        for (int p = (n4 << 2) + tid; p < n; p += nthreads) {
            pair_term_packed(packed, ii[p], jj[p], coul[p], a12[p], b6[p], b10[p], ec, ev);
        }
    } else {
        for (int c = tid; c < n4; c += nthreads) {
            intx4   i4 = ((const intx4*)ii)[c];
            intx4   j4 = ((const intx4*)jj)[c];
            floatx4 c4 = ((const floatx4*)coul)[c];
            floatx4 a4 = ((const floatx4*)a12)[c];
            floatx4 b4 = ((const floatx4*)b6)[c];
            floatx4 h4 = ((const floatx4*)b10)[c];
            pair_term_direct(coords, i4.x, j4.x, c4.x, a4.x, b4.x, h4.x, ec, ev);
            pair_term_direct(coords, i4.y, j4.y, c4.y, a4.y, b4.y, h4.y, ec, ev);
            pair_term_direct(coords, i4.z, j4.z, c4.z, a4.z, b4.z, h4.z, ec, ev);
            pair_term_direct(coords, i4.w, j4.w, c4.w, a4.w, b4.w, h4.w, ec, ev);
        }
        for (int p = (n4 << 2) + tid; p < n; p += nthreads) {
            pair_term_direct(coords, ii[p], jj[p], coul[p], a12[p], b6[p], b10[p], ec, ev);
        }
    }
}

__global__ __launch_bounds__(BLOCK) void fused_pair_kernel(
        const float* __restrict__ coords, const float4* __restrict__ packed,
        const int* __restrict__ p_i, const int* __restrict__ p_j,
        const float* __restrict__ p_coul, const float* __restrict__ p_a12,
        const float* __restrict__ p_b6, const float* __restrict__ p_b10, int n_pair,
        const int* __restrict__ q_i, const int* __restrict__ q_j,
        const float* __restrict__ q_coul, const float* __restrict__ q_a12,
        const float* __restrict__ q_b6, const float* __restrict__ q_b10, int n_pair14,
        double* __restrict__ partials) {
    double ec = 0.0, ev = 0.0, ec14 = 0.0, ev14 = 0.0;
    int tid = blockIdx.x * blockDim.x + threadIdx.x;
    int nthreads = gridDim.x * blockDim.x;

    scan_list(coords, packed, p_i, p_j, p_coul, p_a12, p_b6, p_b10, n_pair,
              tid, nthreads, ec, ev);
    scan_list(coords, packed, q_i, q_j, q_coul, q_a12, q_b6, q_b10, n_pair14,
              tid, nthreads, ec14, ev14);

    for (int off = 32; off > 0; off >>= 1) {
        ec   += __shfl_down(ec,   off, 64);
        ev   += __shfl_down(ev,   off, 64);
        ec14 += __shfl_down(ec14, off, 64);
        ev14 += __shfl_down(ev14, off, 64);
    }

    __shared__ double s[BLOCK / 64][4];
    int lane = threadIdx.x & 63;
    int wid  = threadIdx.x >> 6;
    if (lane == 0) { s[wid][0] = ec; s[wid][1] = ev; s[wid][2] = ec14; s[wid][3] = ev14; }
    __syncthreads();

    if (threadIdx.x == 0) {
        double t0 = 0, t1 = 0, t2 = 0, t3 = 0;
        for (int w = 0; w < BLOCK / 64; ++w) {
            t0 += s[w][0]; t1 += s[w][1]; t2 += s[w][2]; t3 += s[w][3];
        }
        double* row = partials + (size_t)blockIdx.x * 4;
        row[0] = t0; row[1] = t1; row[2] = t2; row[3] = t3;
    }
}

__global__ __launch_bounds__(BLOCK) void finalize_kernel(
        const double* __restrict__ partials, int nrows,
        float* __restrict__ out) {
    double acc0 = 0, acc1 = 0, acc2 = 0, acc3 = 0;
    for (int r = threadIdx.x; r < nrows; r += blockDim.x) {
        const double* row = partials + (size_t)r * 4;
        acc0 += row[0]; acc1 += row[1]; acc2 += row[2]; acc3 += row[3];
    }
    for (int off = 32; off > 0; off >>= 1) {
        acc0 += __shfl_down(acc0, off, 64);
        acc1 += __shfl_down(acc1, off, 64);
        acc2 += __shfl_down(acc2, off, 64);
        acc3 += __shfl_down(acc3, off, 64);
    }
    __shared__ double s[BLOCK / 64][4];
    int lane = threadIdx.x & 63;
    int wid  = threadIdx.x >> 6;
    if (lane == 0) { s[wid][0] = acc0; s[wid][1] = acc1; s[wid][2] = acc2; s[wid][3] = acc3; }
    __syncthreads();
    if (threadIdx.x == 0) {
        double t0 = 0, t1 = 0, t2 = 0, t3 = 0;
        for (int w = 0; w < BLOCK / 64; ++w) {
            t0 += s[w][0]; t1 += s[w][1]; t2 += s[w][2]; t3 += s[w][3];
        }
        out[0] = (float)t0; out[1] = (float)t1;
        out[2] = (float)t2; out[3] = (float)t3;
    }
}

extern "C" void kernel_launch(void* const* d_in, const int* in_sizes, int n_in,
                              void* d_out, int out_size, void* d_ws, size_t ws_size,
                              hipStream_t stream) {
    const float* coords = (const float*)d_in[0];
    int natom = in_sizes[0] / 3;

    const int*   p_i    = (const int*)d_in[1];
    const int*   p_j    = (const int*)d_in[2];
    const float* p_coul = (const float*)d_in[3];
    const float* p_a12  = (const float*)d_in[4];
    const float* p_b6   = (const float*)d_in[5];
    const float* p_b10  = (const float*)d_in[6];
    int n_pair = in_sizes[1];

    const int*   q_i    = (const int*)d_in[7];
    const int*   q_j    = (const int*)d_in[8];
    const float* q_coul = (const float*)d_in[9];
    const float* q_a12  = (const float*)d_in[10];
    const float* q_b6   = (const float*)d_in[11];
    const float* q_b10  = (const float*)d_in[12];
    int n_pair14 = in_sizes[7];

    float* out = (float*)d_out;

    // d_ws layout: [packed coords: natom*16B] [partials: GRID*32B]
    size_t packed_bytes = (size_t)natom * sizeof(float4);
    size_t need = packed_bytes + (size_t)GRID * 4 * sizeof(double);

    float4* packed   = nullptr;
    double* partials = (double*)d_ws;
    int blocks = GRID;

    if (ws_size >= need) {
        packed   = (float4*)d_ws;
        partials = (double*)((char*)d_ws + packed_bytes);
        hipLaunchKernelGGL(pack_coords_kernel,
                           dim3((natom + BLOCK - 1) / BLOCK), dim3(BLOCK), 0, stream,
                           coords, packed, natom);
    } else {
        size_t max_blocks = ws_size / (4 * sizeof(double));
        if ((size_t)blocks > max_blocks) blocks = (int)max_blocks;
        if (blocks < 1) blocks = 1;
    }

    hipLaunchKernelGGL(fused_pair_kernel, dim3(blocks), dim3(BLOCK), 0, stream,
                       coords, packed,
                       p_i, p_j, p_coul, p_a12, p_b6, p_b10, n_pair,
                       q_i, q_j, q_coul, q_a12, q_b6, q_b10, n_pair14,
                       partials);

    hipLaunchKernelGGL(finalize_kernel, dim3(1), dim3(BLOCK), 0, stream,
                       partials, blocks, out);
}